// Round 6
// baseline (2602.805 us; speedup 1.0000x reference)
//
#include <hip/hip_runtime.h>
#include <hip/hip_fp16.h>

#define EMB 32
#define HID 256
#define BATCH 64
#define TT  2048

typedef _Float16 half8_t __attribute__((ext_vector_type(8)));
typedef _Float16 half2_t __attribute__((ext_vector_type(2)));

// ---- d_ws layout ----
// W    : [role 2][chunk 36][tid 512] half8   (589,824 B)
//        chunk c=r*9+jj: gate r of h-index Q=128R+(t>>2), lane l=t&3 cols p=8jj+e:
//        p<8 -> x (W_ih col 8l+p); p in [8,40) -> own-h (W_hh 128R+32l+p-8);
//        p in [40,72) -> partner-h (W_hh 128(1-R)+32l+p-40)
// BIAS : [Q 256][r 4] float
// ACK  : int[128]
#define W_BYTES  (2*36*512*16)
#define BIAS_OFF W_BYTES
#define ACK_OFF  (BIAS_OFF + 4096)

// ---- d_out doubles as h-exchange during the loop ----
// chain b dwords [b*256, b*256+256): role R data at +128R, slot k&1 (64 dw each);
// each half carries tag ((k>>1)&1) in bit0. prep inits slot0=tag0, slot1=tag1.
// Freshness is proven by the TAG, not by the cache that served the load. So the
// poll may opportunistically read through the XCD-local L2 (sc0): if the pair
// shares an XCD (expected under round-robin dispatch), the agent-scope publish
// (sc0|sc1 write-through) is visible there at ~L2 latency. If a wave sees 8
// consecutive stale polls (pairs run in lockstep, so this means "wrong cache
// world", not "partner slow"), it PERMANENTLY escalates to agent-scope (MALL)
// polling — the proven R5 path. Correct in every placement; fast in the
// expected one.

__device__ __forceinline__ float fdot2(half2_t a, half2_t b, float c) {
#if __has_builtin(__builtin_amdgcn_fdot2)
    return __builtin_amdgcn_fdot2(a, b, c, false);
#else
    return c + (float)a[0] * (float)b[0] + (float)a[1] * (float)b[1];
#endif
}

__device__ __forceinline__ float dot8(half8_t w, half8_t x, float acc) {
    acc = fdot2(half2_t{w[0], w[1]}, half2_t{x[0], x[1]}, acc);
    acc = fdot2(half2_t{w[2], w[3]}, half2_t{x[2], x[3]}, acc);
    acc = fdot2(half2_t{w[4], w[5]}, half2_t{x[4], x[5]}, acc);
    acc = fdot2(half2_t{w[6], w[7]}, half2_t{x[6], x[7]}, acc);
    return acc;
}

__device__ __forceinline__ float rcp_fast(float v) {
#if __has_builtin(__builtin_amdgcn_rcpf)
    return __builtin_amdgcn_rcpf(v);
#else
    return 1.0f / v;
#endif
}
__device__ __forceinline__ float sigmoid_fast(float v) {
    return rcp_fast(1.0f + __expf(-v));
}
__device__ __forceinline__ float tanh_fast(float v) {
    v = fminf(fmaxf(v, -15.0f), 15.0f);
    float e = __expf(2.0f * v);
    return (e - 1.0f) * rcp_fast(e + 1.0f);
}

// LDS-only barrier: no vmcnt drain — publish stores / polls stay in flight.
__device__ __forceinline__ void barrier_lds() {
    asm volatile("s_waitcnt lgkmcnt(0)\n\ts_barrier" ::: "memory");
}

__device__ __forceinline__ float quad_reduce(float v) {
    int t = __builtin_amdgcn_mov_dpp(__float_as_int(v), 0xB1, 0xF, 0xF, true);
    v += __int_as_float(t);
    t = __builtin_amdgcn_mov_dpp(__float_as_int(v), 0x4E, 0xF, 0xF, true);
    v += __int_as_float(t);
    return v;
}

// mode 0: sc0/volatile (L1-bypass, XCD-local L2) — fast same-XCD path.
// mode 1: agent scope (MALL) — always-correct fallback.
__device__ __forceinline__ unsigned int poll_load(const unsigned int* p, int mode) {
    if (mode)
        return __hip_atomic_load(p, __ATOMIC_RELAXED, __HIP_MEMORY_SCOPE_AGENT);
    return *(volatile const unsigned int*)p;
}

__device__ __forceinline__ int gate_row(int r, int Q) {
    return r == 0 ? Q : r == 1 ? 256 + Q : r == 2 ? 512 + Q : 768 + Q;
}

// ---- prep (identical layout to R4/R5) ----
__global__ void prep_kernel(const float* __restrict__ W_ih,
                            const float* __restrict__ W_hh,
                            const float* __restrict__ b_ih,
                            const float* __restrict__ b_hh,
                            char* __restrict__ ws,
                            unsigned int* __restrict__ outw) {
    int bid = blockIdx.x, t = threadIdx.x;
    if (bid < 72) {
        int R = bid / 36, c = bid % 36;
        int r = c / 9, jj = c % 9;
        int Q = 128 * R + (t >> 2), l = t & 3;
        int row = gate_row(r, Q);
        half8_t v;
#pragma unroll
        for (int e = 0; e < 8; ++e) {
            int p = 8 * jj + e;
            float f;
            if (p < 8)       f = W_ih[row * EMB + 8 * l + p];
            else if (p < 40) f = W_hh[row * HID + 128 * R + 32 * l + (p - 8)];
            else             f = W_hh[row * HID + 128 * (1 - R) + 32 * l + (p - 40)];
            v[e] = (_Float16)f;
        }
        ((half8_t*)ws)[((size_t)bid) * 512 + t] = v;
    } else if (bid == 72) {
        float* bias = (float*)(ws + BIAS_OFF);
        for (int i = t; i < 1024; i += 512) {
            int Q = i >> 2, r = i & 3;
            int row = gate_row(r, Q);
            bias[i] = b_ih[row] + b_hh[row];
        }
    } else {
        int g = (bid - 73) * 512 + t;
        unsigned int val = ((g >> 6) & 1) ? 0x00010001u : 0u;
        outw[g] = val;
    }
}

// ---- recurrent kernel: 128 blocks (2 per chain), 512 threads ----
__global__ __launch_bounds__(512, 2) void rnn_kernel(const int* __restrict__ x,
                                                     const int* __restrict__ lengths,
                                                     const float* __restrict__ emb,
                                                     char* __restrict__ ws,
                                                     float* __restrict__ out_) {
    __shared__ __align__(16) _Float16 xhbuf[2][320];

    const int bid  = blockIdx.x;
    const int role = bid >> 6;
    const int b    = bid & 63;
    const int tid  = threadIdx.x;
    const int q    = tid >> 2;
    const int l    = tid & 3;
    const int Q    = 128 * role + q;

    half8_t w[4][9];
    {
        const half8_t* Wp = (const half8_t*)ws + (size_t)role * 36 * 512;
#pragma unroll
        for (int r = 0; r < 4; ++r)
#pragma unroll
            for (int jj = 0; jj < 9; ++jj) w[r][jj] = Wp[(r * 9 + jj) * 512 + tid];
    }
    float4 bs = *(const float4*)(ws + BIAS_OFF + (size_t)Q * 16);

    unsigned int* exch = (unsigned int*)out_ + (size_t)b * 256;
    unsigned int* mine = exch + role * 128;
    unsigned int* part = exch + (1 - role) * 128;

    int L = lengths[b];
    if (L > TT) L = TT;
    if (L < 1) L = 1;
    const int* __restrict__ xb = x + b * TT;

    if (tid < 320) xhbuf[0][tid] = (_Float16)0.0f;
    __syncthreads();
    if (tid < EMB) {
        float e0 = emb[xb[0] * EMB + tid];
        xhbuf[0][72 * (tid >> 3) + (tid & 7)] = (_Float16)e0;
    }
    __syncthreads();

    float cc = 0.0f, hh = 0.0f;

    // prologue: own+x partials for step 0
    float p0 = 0.f, p1 = 0.f, p2 = 0.f, p3 = 0.f;
    {
        const _Float16* cur = xhbuf[0];
        half8_t xv[5];
#pragma unroll
        for (int jj = 0; jj < 5; ++jj) xv[jj] = *(const half8_t*)(cur + 72 * l + 8 * jj);
#pragma unroll
        for (int jj = 0; jj < 5; ++jj) {
            p0 = dot8(w[0][jj], xv[jj], p0);
            p1 = dot8(w[1][jj], xv[jj], p1);
            p2 = dot8(w[2][jj], xv[jj], p2);
            p3 = dot8(w[3][jj], xv[jj], p3);
        }
    }

    int mode = 0;   // wave0-uniform poll mode; sticky-escalates to agent scope

#pragma unroll 1
    for (int t = 0; t < L; ++t) {
        const _Float16* __restrict__ cur = xhbuf[t & 1];
        _Float16* __restrict__ nxt = xhbuf[(t + 1) & 1];

        float ev = 0.0f;
        if (tid >= 64 && tid < 64 + EMB) {
            int nt = (t + 1 < L) ? xb[t + 1] : 0;
            ev = emb[nt * EMB + (tid - 64)];
        }

        // 1. partner-col dots (jj 5..8) finish the gate pre-activations
        float a0 = p0, a1 = p1, a2 = p2, a3 = p3;
        {
            half8_t xv[4];
#pragma unroll
            for (int jj = 0; jj < 4; ++jj)
                xv[jj] = *(const half8_t*)(cur + 72 * l + 40 + 8 * jj);
#pragma unroll
            for (int jj = 0; jj < 4; ++jj) {
                a0 = dot8(w[0][5 + jj], xv[jj], a0);
                a1 = dot8(w[1][5 + jj], xv[jj], a1);
                a2 = dot8(w[2][5 + jj], xv[jj], a2);
                a3 = dot8(w[3][5 + jj], xv[jj], a3);
            }
        }

        // 2. reduce + activations
        a0 = quad_reduce(a0);
        a1 = quad_reduce(a1);
        a2 = quad_reduce(a2);
        a3 = quad_reduce(a3);
        float iv = sigmoid_fast(a0 + bs.x);
        float fv = sigmoid_fast(a1 + bs.y);
        float gv = tanh_fast(a2 + bs.z);
        float ov = sigmoid_fast(a3 + bs.w);
        cc = fv * cc + iv * gv;
        hh = ov * tanh_fast(cc);

        const unsigned int tg = ((unsigned)(t + 1) >> 1) & 1u;
        const int ps_ = (t + 1) & 1;

        // 3. publish own h(t+1): agent store (sc0|sc1) — visible at MALL always,
        //    and (expected) refreshes/updates the shared XCD L2 for the fast poll
        _Float16 hf = (_Float16)hh;
        unsigned short hb = __builtin_bit_cast(unsigned short, hf);
        unsigned int tb = (unsigned int)((hb & 0xFFFEu) | tg);
        unsigned int nb = (unsigned int)__builtin_amdgcn_mov_dpp((int)tb, 0x104, 0xF, 0xF, true);
        if ((tid & 7) == 0) {
            unsigned int dw = tb | (nb << 16);
            __hip_atomic_store(mine + ps_ * 64 + (tid >> 3), dw,
                               __ATOMIC_RELAXED, __HIP_MEMORY_SCOPE_AGENT);
        }

        // 4. own-h(t+1) and x(t+1) into next buffer
        if (l == 0) nxt[72 * (q >> 5) + 8 + (q & 31)] = hf;
        if (tid >= 64 && tid < 64 + EMB) {
            int k = tid - 64;
            nxt[72 * (k >> 3) + (k & 7)] = (_Float16)ev;
        }
        barrier_lds();   // A

        // 5. first partner poll, then own+x dots for step t+1 in its shadow
        unsigned int fdw = 0;
        const unsigned int* psp = part + ps_ * 64;
        if (tid < 64) fdw = poll_load(psp + tid, mode);

        p0 = 0.f; p1 = 0.f; p2 = 0.f; p3 = 0.f;
        {
            half8_t xv[5];
#pragma unroll
            for (int jj = 0; jj < 5; ++jj)
                xv[jj] = *(const half8_t*)(nxt + 72 * l + 8 * jj);
#pragma unroll
            for (int jj = 0; jj < 5; ++jj) {
                p0 = dot8(w[0][jj], xv[jj], p0);
                p1 = dot8(w[1][jj], xv[jj], p1);
                p2 = dot8(w[2][jj], xv[jj], p2);
                p3 = dot8(w[3][jj], xv[jj], p3);
            }
        }

        // 6. wave0: finish the spin (sticky sc0->agent escalation), land partner h
        if (tid < 64) {
            unsigned int dw = fdw;
            int tries = 0;
            while (!__all(((dw & 1u) == tg) && (((dw >> 16) & 1u) == tg))) {
                ++tries;
                if (mode == 0 && tries > 8) mode = 1;   // sticky: wrong-cache world
                if (mode) __builtin_amdgcn_s_sleep(1);
                if (tries > (1 << 20)) break;
                dw = poll_load(psp + tid, mode);
            }
            unsigned short h0 = (unsigned short)(dw & 0xFFFEu);
            unsigned short h1 = (unsigned short)((dw >> 16) & 0xFFFEu);
            int j0 = 2 * tid, j1 = 2 * tid + 1;
            nxt[72 * (j0 >> 5) + 40 + (j0 & 31)] = __builtin_bit_cast(_Float16, h0);
            nxt[72 * (j1 >> 5) + 40 + (j1 & 31)] = __builtin_bit_cast(_Float16, h1);
        }
        barrier_lds();   // B
    }

    // end handshake: partner done reading my d_out region -> safe to overwrite
    int* ack = (int*)(ws + ACK_OFF);
    if (tid == 0)
        __hip_atomic_store(&ack[bid], L, __ATOMIC_RELEASE, __HIP_MEMORY_SCOPE_AGENT);
    if (tid == 0) {
        int tries = 0;
        while (__hip_atomic_load(&ack[bid ^ 64], __ATOMIC_ACQUIRE, __HIP_MEMORY_SCOPE_AGENT) != L) {
            if (++tries > (1 << 20)) break;
            __builtin_amdgcn_s_sleep(8);
        }
    }
    __syncthreads();
    if (l == 0) out_[(size_t)b * 256 + 128 * role + q] = hh;
}

extern "C" void kernel_launch(void* const* d_in, const int* in_sizes, int n_in,
                              void* d_out, int out_size, void* d_ws, size_t ws_size,
                              hipStream_t stream) {
    const int*   x       = (const int*)d_in[0];
    const int*   lengths = (const int*)d_in[1];
    const float* emb     = (const float*)d_in[2];
    const float* W_ih    = (const float*)d_in[3];
    const float* W_hh    = (const float*)d_in[4];
    const float* b_ih    = (const float*)d_in[5];
    const float* b_hh    = (const float*)d_in[6];

    prep_kernel<<<105, 512, 0, stream>>>(W_ih, W_hh, b_ih, b_hh,
                                         (char*)d_ws, (unsigned int*)d_out);
    rnn_kernel<<<128, 512, 0, stream>>>(x, lengths, emb, (char*)d_ws, (float*)d_out);
}

// Round 7
// 2519.985 us; speedup vs baseline: 1.0329x; 1.0329x over previous
//
#include <hip/hip_runtime.h>
#include <hip/hip_fp16.h>

#define EMB 32
#define HID 256
#define BATCH 64
#define TT  2048

typedef _Float16 half8_t __attribute__((ext_vector_type(8)));
typedef _Float16 half2_t __attribute__((ext_vector_type(2)));

// ---- d_ws layout ----
// W    : [role 2][chunk 36][tid 512] half8   (589,824 B)
//        chunk c=r*9+jj: gate r of h-index Q=128R+(t>>2), lane l=t&3 cols p=8jj+e:
//        p<8 -> x (W_ih col 8l+p); p in [8,40) -> own-h (W_hh 128R+32l+p-8);
//        p in [40,72) -> partner-h (W_hh 128(1-R)+32l+p-40)
// BIAS : [Q 256][r 4] float
// ACK  : int[128]
// FAST : same-XCD exchange mirror, 64 chains x 256 dwords (64 KB)
#define W_BYTES  (2*36*512*16)
#define BIAS_OFF W_BYTES                 // 589824
#define ACK_OFF  (BIAS_OFF + 4096)       // 593920
#define FAST_OFF (ACK_OFF + 1024)        // 594944 (16B aligned)

// ---- exchange protocol ----
// SLOW region = d_out (agent/MALL, always correct — R5-proven).
// FAST region = d_ws FAST (plain stores land in the producer-XCD L2 via
// write-through L1; sc0/volatile polls bypass L1 and hit that L2 if the pair
// shares an XCD). Freshness is proven by the per-half tag bit, never by which
// cache served the load. A wave seeing 12 consecutive stale FAST polls is in
// a cross-XCD world (plain stores are never probed cross-XCD) and PERMANENTLY
// escalates to SLOW polling. Correct in every placement; fast in the expected
// (b, b+64)->same-XCD round-robin placement.
// Layout per chain b (both regions): dwords [b*256, b*256+256): role R data at
// +128R, slot k&1 (64 dw). tag ((k>>1)&1) in bit0 of each half.
// prep inits slot0 dwords = 0 (tag0), slot1 = 0x00010001 (tag1): first uses
// (slot1 gets h(1) tag0; slot0 gets h(2) tag1) never false-match.

__device__ __forceinline__ float fdot2(half2_t a, half2_t b, float c) {
#if __has_builtin(__builtin_amdgcn_fdot2)
    return __builtin_amdgcn_fdot2(a, b, c, false);
#else
    return c + (float)a[0] * (float)b[0] + (float)a[1] * (float)b[1];
#endif
}

__device__ __forceinline__ float dot8(half8_t w, half8_t x, float acc) {
    acc = fdot2(half2_t{w[0], w[1]}, half2_t{x[0], x[1]}, acc);
    acc = fdot2(half2_t{w[2], w[3]}, half2_t{x[2], x[3]}, acc);
    acc = fdot2(half2_t{w[4], w[5]}, half2_t{x[4], x[5]}, acc);
    acc = fdot2(half2_t{w[6], w[7]}, half2_t{x[6], x[7]}, acc);
    return acc;
}

__device__ __forceinline__ float rcp_fast(float v) {
#if __has_builtin(__builtin_amdgcn_rcpf)
    return __builtin_amdgcn_rcpf(v);
#else
    return 1.0f / v;
#endif
}
__device__ __forceinline__ float sigmoid_fast(float v) {
    return rcp_fast(1.0f + __expf(-v));
}
__device__ __forceinline__ float tanh_fast(float v) {
    v = fminf(fmaxf(v, -15.0f), 15.0f);
    float e = __expf(2.0f * v);
    return (e - 1.0f) * rcp_fast(e + 1.0f);
}

// LDS-only barrier: no vmcnt drain — publish stores / polls stay in flight.
__device__ __forceinline__ void barrier_lds() {
    asm volatile("s_waitcnt lgkmcnt(0)\n\ts_barrier" ::: "memory");
}

__device__ __forceinline__ float quad_reduce(float v) {
    int t = __builtin_amdgcn_mov_dpp(__float_as_int(v), 0xB1, 0xF, 0xF, true);
    v += __int_as_float(t);
    t = __builtin_amdgcn_mov_dpp(__float_as_int(v), 0x4E, 0xF, 0xF, true);
    v += __int_as_float(t);
    return v;
}

__device__ __forceinline__ unsigned int load_fast(const unsigned int* p) {
    return *(volatile const unsigned int*)p;      // sc0: L1-bypass, L2-hit
}
__device__ __forceinline__ unsigned int load_slow(const unsigned int* p) {
    return __hip_atomic_load(p, __ATOMIC_RELAXED, __HIP_MEMORY_SCOPE_AGENT);
}

__device__ __forceinline__ int gate_row(int r, int Q) {
    return r == 0 ? Q : r == 1 ? 256 + Q : r == 2 ? 512 + Q : 768 + Q;
}

// ---- prep: weights/bias (as R4/R5) + SLOW (d_out) + FAST (d_ws) tag init ----
// grid 137 x 512: 0..71 weights; 72 bias; 73..104 SLOW init; 105..136 FAST init
__global__ void prep_kernel(const float* __restrict__ W_ih,
                            const float* __restrict__ W_hh,
                            const float* __restrict__ b_ih,
                            const float* __restrict__ b_hh,
                            char* __restrict__ ws,
                            unsigned int* __restrict__ outw) {
    int bid = blockIdx.x, t = threadIdx.x;
    if (bid < 72) {
        int R = bid / 36, c = bid % 36;
        int r = c / 9, jj = c % 9;
        int Q = 128 * R + (t >> 2), l = t & 3;
        int row = gate_row(r, Q);
        half8_t v;
#pragma unroll
        for (int e = 0; e < 8; ++e) {
            int p = 8 * jj + e;
            float f;
            if (p < 8)       f = W_ih[row * EMB + 8 * l + p];
            else if (p < 40) f = W_hh[row * HID + 128 * R + 32 * l + (p - 8)];
            else             f = W_hh[row * HID + 128 * (1 - R) + 32 * l + (p - 40)];
            v[e] = (_Float16)f;
        }
        ((half8_t*)ws)[((size_t)bid) * 512 + t] = v;
    } else if (bid == 72) {
        float* bias = (float*)(ws + BIAS_OFF);
        for (int i = t; i < 1024; i += 512) {
            int Q = i >> 2, r = i & 3;
            int row = gate_row(r, Q);
            bias[i] = b_ih[row] + b_hh[row];
        }
    } else if (bid < 105) {
        int g = (bid - 73) * 512 + t;                  // SLOW tags in d_out
        outw[g] = ((g >> 6) & 1) ? 0x00010001u : 0u;
    } else {
        int g = (bid - 105) * 512 + t;                 // FAST tags in d_ws
        ((unsigned int*)(ws + FAST_OFF))[g] = ((g >> 6) & 1) ? 0x00010001u : 0u;
    }
}

// ---- recurrent kernel: 128 blocks (2 per chain), 512 threads ----
__global__ __launch_bounds__(512, 2) void rnn_kernel(const int* __restrict__ x,
                                                     const int* __restrict__ lengths,
                                                     const float* __restrict__ emb,
                                                     char* __restrict__ ws,
                                                     float* __restrict__ out_) {
    __shared__ __align__(16) _Float16 xhbuf[2][320];

    const int bid  = blockIdx.x;
    const int role = bid >> 6;
    const int b    = bid & 63;
    const int tid  = threadIdx.x;
    const int q    = tid >> 2;
    const int l    = tid & 3;
    const int Q    = 128 * role + q;

    half8_t w[4][9];
    {
        const half8_t* Wp = (const half8_t*)ws + (size_t)role * 36 * 512;
#pragma unroll
        for (int r = 0; r < 4; ++r)
#pragma unroll
            for (int jj = 0; jj < 9; ++jj) w[r][jj] = Wp[(r * 9 + jj) * 512 + tid];
    }
    float4 bs = *(const float4*)(ws + BIAS_OFF + (size_t)Q * 16);

    unsigned int* sexch = (unsigned int*)out_ + (size_t)b * 256;          // SLOW (MALL)
    unsigned int* fexch = (unsigned int*)(ws + FAST_OFF) + (size_t)b * 256; // FAST (L2)
    unsigned int* smine = sexch + role * 128;
    unsigned int* spart = sexch + (1 - role) * 128;
    unsigned int* fmine = fexch + role * 128;
    unsigned int* fpart = fexch + (1 - role) * 128;

    int L = lengths[b];
    if (L > TT) L = TT;
    if (L < 1) L = 1;
    const int* __restrict__ xb = x + b * TT;

    if (tid < 320) xhbuf[0][tid] = (_Float16)0.0f;
    __syncthreads();
    if (tid < EMB) {
        float e0 = emb[xb[0] * EMB + tid];
        xhbuf[0][72 * (tid >> 3) + (tid & 7)] = (_Float16)e0;
    }
    __syncthreads();

    float cc = 0.0f, hh = 0.0f;

    // prologue: own+x partials for step 0
    float p0 = 0.f, p1 = 0.f, p2 = 0.f, p3 = 0.f;
    {
        const _Float16* cur = xhbuf[0];
        half8_t xv[5];
#pragma unroll
        for (int jj = 0; jj < 5; ++jj) xv[jj] = *(const half8_t*)(cur + 72 * l + 8 * jj);
#pragma unroll
        for (int jj = 0; jj < 5; ++jj) {
            p0 = dot8(w[0][jj], xv[jj], p0);
            p1 = dot8(w[1][jj], xv[jj], p1);
            p2 = dot8(w[2][jj], xv[jj], p2);
            p3 = dot8(w[3][jj], xv[jj], p3);
        }
    }

    int mode = 0;   // wave0: 0 = FAST (same-XCD L2), 1 = SLOW (MALL), sticky

#pragma unroll 1
    for (int t = 0; t < L; ++t) {
        const _Float16* __restrict__ cur = xhbuf[t & 1];
        _Float16* __restrict__ nxt = xhbuf[(t + 1) & 1];

        float ev = 0.0f;
        if (tid >= 64 && tid < 64 + EMB) {
            int nt = (t + 1 < L) ? xb[t + 1] : 0;
            ev = emb[nt * EMB + (tid - 64)];
        }

        // 1. partner-col dots (jj 5..8) finish the gate pre-activations
        float a0 = p0, a1 = p1, a2 = p2, a3 = p3;
        {
            half8_t xv[4];
#pragma unroll
            for (int jj = 0; jj < 4; ++jj)
                xv[jj] = *(const half8_t*)(cur + 72 * l + 40 + 8 * jj);
#pragma unroll
            for (int jj = 0; jj < 4; ++jj) {
                a0 = dot8(w[0][5 + jj], xv[jj], a0);
                a1 = dot8(w[1][5 + jj], xv[jj], a1);
                a2 = dot8(w[2][5 + jj], xv[jj], a2);
                a3 = dot8(w[3][5 + jj], xv[jj], a3);
            }
        }

        // 2. reduce + activations
        a0 = quad_reduce(a0);
        a1 = quad_reduce(a1);
        a2 = quad_reduce(a2);
        a3 = quad_reduce(a3);
        float iv = sigmoid_fast(a0 + bs.x);
        float fv = sigmoid_fast(a1 + bs.y);
        float gv = tanh_fast(a2 + bs.z);
        float ov = sigmoid_fast(a3 + bs.w);
        cc = fv * cc + iv * gv;
        hh = ov * tanh_fast(cc);

        const unsigned int tg = ((unsigned)(t + 1) >> 1) & 1u;
        const int ps_ = (t + 1) & 1;

        // 3. dual-publish own h(t+1):
        //    FAST: plain store -> producer-XCD L2 (write-through L1)
        //    SLOW: agent store -> MALL (always-correct fallback)
        _Float16 hf = (_Float16)hh;
        unsigned short hb = __builtin_bit_cast(unsigned short, hf);
        unsigned int tb = (unsigned int)((hb & 0xFFFEu) | tg);
        unsigned int nb = (unsigned int)__builtin_amdgcn_mov_dpp((int)tb, 0x104, 0xF, 0xF, true);
        if ((tid & 7) == 0) {
            unsigned int dw = tb | (nb << 16);
            int o = ps_ * 64 + (tid >> 3);
            __hip_atomic_store(fmine + o, dw, __ATOMIC_RELAXED, __HIP_MEMORY_SCOPE_WORKGROUP);
            __hip_atomic_store(smine + o, dw, __ATOMIC_RELAXED, __HIP_MEMORY_SCOPE_AGENT);
        }

        // 4. own-h(t+1) and x(t+1) into next buffer
        if (l == 0) nxt[72 * (q >> 5) + 8 + (q & 31)] = hf;
        if (tid >= 64 && tid < 64 + EMB) {
            int k = tid - 64;
            nxt[72 * (k >> 3) + (k & 7)] = (_Float16)ev;
        }
        barrier_lds();   // A

        // 5. first partner poll, then own+x dots for step t+1 in its shadow
        unsigned int fdw = 0;
        const unsigned int* fp = fpart + ps_ * 64 + tid;
        const unsigned int* sp = spart + ps_ * 64 + tid;
        if (tid < 64) fdw = mode ? load_slow(sp) : load_fast(fp);

        p0 = 0.f; p1 = 0.f; p2 = 0.f; p3 = 0.f;
        {
            half8_t xv[5];
#pragma unroll
            for (int jj = 0; jj < 5; ++jj)
                xv[jj] = *(const half8_t*)(nxt + 72 * l + 8 * jj);
#pragma unroll
            for (int jj = 0; jj < 5; ++jj) {
                p0 = dot8(w[0][jj], xv[jj], p0);
                p1 = dot8(w[1][jj], xv[jj], p1);
                p2 = dot8(w[2][jj], xv[jj], p2);
                p3 = dot8(w[3][jj], xv[jj], p3);
            }
        }

        // 6. wave0: finish the spin (sticky FAST->SLOW escalation), land partner h
        if (tid < 64) {
            unsigned int dw = fdw;
            int tries = 0;
            while (!__all(((dw & 1u) == tg) && (((dw >> 16) & 1u) == tg))) {
                ++tries;
                if (mode == 0 && tries > 12) mode = 1;  // cross-XCD world: escalate
                if (tries > (1 << 20)) break;
                if (mode) { __builtin_amdgcn_s_sleep(1); dw = load_slow(sp); }
                else      dw = load_fast(fp);
            }
            unsigned short h0 = (unsigned short)(dw & 0xFFFEu);
            unsigned short h1 = (unsigned short)((dw >> 16) & 0xFFFEu);
            int j0 = 2 * tid, j1 = 2 * tid + 1;
            nxt[72 * (j0 >> 5) + 40 + (j0 & 31)] = __builtin_bit_cast(_Float16, h0);
            nxt[72 * (j1 >> 5) + 40 + (j1 & 31)] = __builtin_bit_cast(_Float16, h1);
        }
        barrier_lds();   // B
    }

    // end handshake: partner done reading my d_out region -> safe to overwrite
    int* ack = (int*)(ws + ACK_OFF);
    if (tid == 0)
        __hip_atomic_store(&ack[bid], L, __ATOMIC_RELEASE, __HIP_MEMORY_SCOPE_AGENT);
    if (tid == 0) {
        int tries = 0;
        while (__hip_atomic_load(&ack[bid ^ 64], __ATOMIC_ACQUIRE, __HIP_MEMORY_SCOPE_AGENT) != L) {
            if (++tries > (1 << 20)) break;
            __builtin_amdgcn_s_sleep(8);
        }
    }
    __syncthreads();
    if (l == 0) out_[(size_t)b * 256 + 128 * role + q] = hh;
}

extern "C" void kernel_launch(void* const* d_in, const int* in_sizes, int n_in,
                              void* d_out, int out_size, void* d_ws, size_t ws_size,
                              hipStream_t stream) {
    const int*   x       = (const int*)d_in[0];
    const int*   lengths = (const int*)d_in[1];
    const float* emb     = (const float*)d_in[2];
    const float* W_ih    = (const float*)d_in[3];
    const float* W_hh    = (const float*)d_in[4];
    const float* b_ih    = (const float*)d_in[5];
    const float* b_hh    = (const float*)d_in[6];

    prep_kernel<<<137, 512, 0, stream>>>(W_ih, W_hh, b_ih, b_hh,
                                         (char*)d_ws, (unsigned int*)d_out);
    rnn_kernel<<<128, 512, 0, stream>>>(x, lengths, emb, (char*)d_ws, (float*)d_out);
}